// Round 1
// baseline (118.718 us; speedup 1.0000x reference)
//
#include <hip/hip_runtime.h>
#include <hip/hip_cooperative_groups.h>

namespace cg = cooperative_groups;

// Problem constants (fixed by reference)
constexpr int B = 4, T = 8, V = 256, F = 64;
constexpr int BT = B * T;            // 32 (b,t) slices
constexpr int CHUNK = 16;            // rows of i per block
constexpr int NCHUNK = V / CHUNK;    // 16 -> grid = 32*16 = 512 blocks

// One cooperative kernel:
//  phase 1: thread tid owns column j=tid of one (b,t) tile, sweeps CHUNK rows i.
//           score(i,j) = sum_f |x_i[f]-x_j[f]|*a[f]; tmp = exp(max(score,0)).
//           By symmetry colsum over i of tmp[.,j] contributes to denom[j]
//           (denom[i] = sum_k tmpS[k,i] = sum_k tmpS[i,k]).
//  grid.sync()
//  phase 2: S[i,j] = tmp(i,j) / denom[i], tmp held in registers across sync.
__global__ __launch_bounds__(256, 2)
void gl_fused(const float* __restrict__ X, const float* __restrict__ A,
              float* __restrict__ OUT, float* __restrict__ denom)
{
    const int tid = threadIdx.x;           // column j
    const int blk = blockIdx.x;
    const int bt  = blk / NCHUNK;
    const int ic  = blk % NCHUNK;
    const int i0  = ic * CHUNK;

    const float* xbt = X + (size_t)bt * V * F;   // [256][64] tile

    __shared__ float sxi[CHUNK][F];        // 4 KB: the CHUNK "i" rows

    // stage chunk rows into LDS: CHUNK*F = 1024 floats, 256 threads x float4
    {
        const float4 v = reinterpret_cast<const float4*>(xbt + (size_t)i0 * F)[tid];
        reinterpret_cast<float4*>(&sxi[0][0])[tid] = v;
    }

    // own column x_j -> registers (64 VGPRs)
    float xr[F];
    {
        const float4* src = reinterpret_cast<const float4*>(xbt + (size_t)tid * F);
#pragma unroll
        for (int k = 0; k < F / 4; ++k) {
            const float4 v = src[k];
            xr[4*k+0] = v.x; xr[4*k+1] = v.y; xr[4*k+2] = v.z; xr[4*k+3] = v.w;
        }
    }

    // a -> uniform loads (compiler scalarizes to SGPRs)
    float af[F];
#pragma unroll
    for (int k = 0; k < F / 4; ++k) {
        const float4 v = reinterpret_cast<const float4*>(A)[k];
        af[4*k+0] = v.x; af[4*k+1] = v.y; af[4*k+2] = v.z; af[4*k+3] = v.w;
    }

    __syncthreads();

    float tmp[CHUNK];
    float colsum = 0.0f;
#pragma unroll
    for (int r = 0; r < CHUNK; ++r) {
        float s = 0.0f;
#pragma unroll
        for (int f = 0; f < F; ++f)
            s += fabsf(xr[f] - sxi[r][f]) * af[f];
        const float e = __expf(fmaxf(s, 0.0f));
        tmp[r] = e;
        colsum += e;
    }

    // partial column-sum -> denom[j]  (device-scope atomic by default)
    atomicAdd(&denom[bt * V + tid], colsum);

    cg::this_grid().sync();

    // normalize: S[bt, i0+r, tid] = tmp[r] / denom[bt, i0+r]
    const float* drow = denom + bt * V;
    float* obase = OUT + (((size_t)bt * V + i0) * V) + tid;
#pragma unroll
    for (int r = 0; r < CHUNK; ++r) {
        const float d = drow[i0 + r];
        obase[(size_t)r * V] = tmp[r] * __builtin_amdgcn_rcpf(d);
    }
}

extern "C" void kernel_launch(void* const* d_in, const int* in_sizes, int n_in,
                              void* d_out, int out_size, void* d_ws, size_t ws_size,
                              hipStream_t stream)
{
    const float* X = (const float*)d_in[0];   // [B,T,V,F] fp32
    const float* A = (const float*)d_in[1];   // [F,1]     fp32
    float* OUT   = (float*)d_out;             // [B,T,V,V] fp32
    float* denom = (float*)d_ws;              // BT*V floats of scratch

    // ws is re-poisoned to 0xAA before every launch -> zero the denom array
    hipMemsetAsync(denom, 0, (size_t)BT * V * sizeof(float), stream);

    void* args[] = { (void*)&X, (void*)&A, (void*)&OUT, (void*)&denom };
    dim3 grid(BT * NCHUNK), block(256);
    hipLaunchCooperativeKernel((void*)gl_fused, grid, block, args, 0, stream);
}

// Round 3
// 88.222 us; speedup vs baseline: 1.3457x; 1.3457x over previous
//
#include <hip/hip_runtime.h>

// Problem constants (fixed by reference)
constexpr int B = 4, T = 8, V = 256, F = 64;
constexpr int BT = B * T;            // 32 (b,t) slices
constexpr int CHUNK = 8;             // rows of i per block
constexpr int NCHUNK = V / CHUNK;    // 32 -> grid = 32*32 = 1024 blocks (4 blocks/CU)

// Single regular kernel. Block = (bt, 8-row chunk). Thread tid owns column j=tid.
// score(i,j) = sum_f |x_i[f]-x_j[f]|*a[f] is SYMMETRIC, so
// denom[i] (= column-i sum in the reference) equals the row-i sum, which this
// block computes in full -> denominator is a block-level reduction. No grid
// sync, no atomics, no workspace.
__global__ __launch_bounds__(256)
void gl_fused(const float* __restrict__ X, const float* __restrict__ A,
              float* __restrict__ OUT)
{
    const int tid = threadIdx.x;           // column j
    const int bt  = blockIdx.x / NCHUNK;
    const int ic  = blockIdx.x % NCHUNK;
    const int i0  = ic * CHUNK;

    const float* xbt = X + (size_t)bt * V * F;   // [256][64] tile

    __shared__ float sxi[CHUNK * F];       // 2 KB: the CHUNK "i" rows
    __shared__ float wpart[4][CHUNK];      // per-wave partial row sums
    __shared__ float rden[CHUNK];          // reciprocal denominators

    // stage chunk rows into LDS: CHUNK*F = 512 floats, first 128 threads x float4
    if (tid < CHUNK * F / 4)
        reinterpret_cast<float4*>(sxi)[tid] =
            reinterpret_cast<const float4*>(xbt + (size_t)i0 * F)[tid];

    // a -> uniform address, compiler scalarizes to SGPRs
    float af[F];
#pragma unroll
    for (int k = 0; k < F / 4; ++k) {
        const float4 v = reinterpret_cast<const float4*>(A)[k];
        af[4*k+0] = v.x; af[4*k+1] = v.y; af[4*k+2] = v.z; af[4*k+3] = v.w;
    }

    __syncthreads();

    float acc[CHUNK];
#pragma unroll
    for (int r = 0; r < CHUNK; ++r) acc[r] = 0.0f;

    // stream own column in float4 chunks; CHUNK independent fma chains for ILP.
    // srow addresses are wave-uniform -> LDS broadcast, conflict-free.
    const float4* colp = reinterpret_cast<const float4*>(xbt + (size_t)tid * F);
#pragma unroll
    for (int k = 0; k < F / 4; ++k) {
        const float4 xv = colp[k];
#pragma unroll
        for (int r = 0; r < CHUNK; ++r) {
            const float* srow = &sxi[r * F + 4 * k];
            float s = acc[r];
            s = fmaf(fabsf(xv.x - srow[0]), af[4*k+0], s);
            s = fmaf(fabsf(xv.y - srow[1]), af[4*k+1], s);
            s = fmaf(fabsf(xv.z - srow[2]), af[4*k+2], s);
            s = fmaf(fabsf(xv.w - srow[3]), af[4*k+3], s);
            acc[r] = s;
        }
    }

    float tmp[CHUNK];
#pragma unroll
    for (int r = 0; r < CHUNK; ++r)
        tmp[r] = __expf(fmaxf(acc[r], 0.0f));

    // block reduction: row sum = denominator (symmetry)
    const int lane = tid & 63;
    const int wv   = tid >> 6;
#pragma unroll
    for (int r = 0; r < CHUNK; ++r) {
        float v = tmp[r];
        v += __shfl_xor(v, 32);
        v += __shfl_xor(v, 16);
        v += __shfl_xor(v, 8);
        v += __shfl_xor(v, 4);
        v += __shfl_xor(v, 2);
        v += __shfl_xor(v, 1);
        if (lane == 0) wpart[wv][r] = v;
    }
    __syncthreads();
    if (tid < CHUNK) {
        const float d = wpart[0][tid] + wpart[1][tid] + wpart[2][tid] + wpart[3][tid];
        rden[tid] = 1.0f / d;
    }
    __syncthreads();

    // S[bt, i0+r, tid] = tmp[r] / denom[i0+r]; consecutive tids -> coalesced
    float* obase = OUT + (((size_t)bt * V + i0) * V) + tid;
#pragma unroll
    for (int r = 0; r < CHUNK; ++r)
        obase[(size_t)r * V] = tmp[r] * rden[r];
}

extern "C" void kernel_launch(void* const* d_in, const int* in_sizes, int n_in,
                              void* d_out, int out_size, void* d_ws, size_t ws_size,
                              hipStream_t stream)
{
    const float* X = (const float*)d_in[0];   // [B,T,V,F] fp32
    const float* A = (const float*)d_in[1];   // [F,1]     fp32
    float* OUT = (float*)d_out;               // [B,T,V,V] fp32

    dim3 grid(BT * NCHUNK), block(256);
    gl_fused<<<grid, block, 0, stream>>>(X, A, OUT);
}